// Round 5
// baseline (290.790 us; speedup 1.0000x reference)
//
#include <hip/hip_runtime.h>

// SSIM (32,3,512,512) fp32, crop 4, 11x11 Gaussian sigma=1.5, per-batch mean.
//
// V5 = V4 math (4 fields {r,d,r2+d2,rd}, folded 255, rcp+Newton) with TH=16
// for occupancy: vs[4][16][84] = 21.5 KB -> 6 blocks/CU (VGPR-capped), 24/32
// waves vs 12/32 at TH=32. Stage A is exactly 1 task/thread (247 tasks),
// stage B exactly 4 px/thread. Extra y-halo work (+24% stage A) is paid for
// by 2.4x latency-hiding headroom — V4 was stall-bound (VALUBusy 45%).

#define IMG   512
#define OUTD  494
#define CB    4
#define TW    64
#define TH    16
#define VSW   84
#define C1F   6.5025f
#define C2F   58.5225f
#define NPIX  732108.0f    // 3*494*494
#define XBLK  8
#define YBLK  31           // ceil(494/16)
#define SLOTS (XBLK*YBLK*3)

__global__ __launch_bounds__(256) void ssim_main(
        const float* __restrict__ raw, const float* __restrict__ dst,
        float* __restrict__ partial) {
    __shared__ float vs[4][TH + 10][VSW];   // 26 rows: 34.9 KB? no: 4*26*84*4 = 34944 B
    __shared__ float red[4];

    const int tid = threadIdx.x;
    const int bc  = blockIdx.z;
    const int b   = bc / 3;
    const int c3  = bc - b * 3;
    const int ty0 = blockIdx.y * TH;
    const int tx0 = blockIdx.x * TW;

    // Gaussian weights: g = exp(-x^2/(2*1.5^2)); g /= sum(g)  (matches jnp)
    float gw[11], gw255[11];
    {
        float s = 0.f;
        #pragma unroll
        for (int k = 0; k < 11; ++k) {
            float x = (float)(k - 5);
            gw[k] = expf(-x * x * (1.0f / 4.5f));
            s += gw[k];
        }
        float inv = 1.0f / s;
        #pragma unroll
        for (int k = 0; k < 11; ++k) { gw[k] *= inv; gw255[k] = gw[k] * 255.0f; }
    }

    const float* rb = raw + (size_t)bc * (IMG * IMG);
    const float* db = dst + (size_t)bc * (IMG * IMG);

    // ---- Stage A: vertical conv. 247 tasks = 13 row-pairs x 19 x-groups,
    //      exactly one per thread (tid < 247). ----
    if (tid < 247) {
        const int rp = tid / 19;
        const int xg = tid - rp * 19;
        int col0 = CB + tx0 + xg * 4;
        if (col0 > IMG - 4) col0 = IMG - 4;      // edge blocks: garbage cols unused
        int row0 = CB + ty0 + rp * 2;
        if (row0 > IMG - 12) row0 = IMG - 12;    // garbage rows unused

        float a0[4][4] = {{0.f}};   // fields {r, d, r2+d2, rd} for vs-row rp*2
        float a1[4][4] = {{0.f}};   // and rp*2+1
        const float* rrow = rb + (size_t)row0 * IMG + col0;
        const float* drow = db + (size_t)row0 * IMG + col0;
        #pragma unroll
        for (int k = 0; k < 12; ++k) {
            const float4 va = *(const float4*)(rrow); rrow += IMG;
            const float4 vc = *(const float4*)(drow); drow += IMG;
            const float A[4]  = {va.x, va.y, va.z, va.w};
            const float Cv[4] = {vc.x, vc.y, vc.z, vc.w};
            float s2[4], pq[4];
            #pragma unroll
            for (int c = 0; c < 4; ++c) {
                s2[c] = fmaf(A[c], A[c], Cv[c] * Cv[c]);
                pq[c] = A[c] * Cv[c];
            }
            if (k < 11) {
                const float w = gw[k], w2 = gw255[k];
                #pragma unroll
                for (int c = 0; c < 4; ++c) {
                    a0[0][c] = fmaf(w,  A[c],  a0[0][c]);
                    a0[1][c] = fmaf(w,  Cv[c], a0[1][c]);
                    a0[2][c] = fmaf(w2, s2[c], a0[2][c]);
                    a0[3][c] = fmaf(w2, pq[c], a0[3][c]);
                }
            }
            if (k >= 1) {
                const float w = gw[k - 1], w2 = gw255[k - 1];
                #pragma unroll
                for (int c = 0; c < 4; ++c) {
                    a1[0][c] = fmaf(w,  A[c],  a1[0][c]);
                    a1[1][c] = fmaf(w,  Cv[c], a1[1][c]);
                    a1[2][c] = fmaf(w2, s2[c], a1[2][c]);
                    a1[3][c] = fmaf(w2, pq[c], a1[3][c]);
                }
            }
        }
        #pragma unroll
        for (int f = 0; f < 4; ++f) {
            *(float4*)&vs[f][rp * 2 + 0][xg * 4] =
                make_float4(a0[f][0], a0[f][1], a0[f][2], a0[f][3]);
            *(float4*)&vs[f][rp * 2 + 1][xg * 4] =
                make_float4(a1[f][0], a1[f][1], a1[f][2], a1[f][3]);
        }
    }
    __syncthreads();

    // ---- Stage B: horizontal conv + SSIM. Thread = 4 cols x 1 row. ----
    const int xg  = tid & 15;
    const int row = tid >> 4;       // 0..15
    const int ox0 = tx0 + xg * 4;
    const int oy  = ty0 + row;
    float m[4][4];
    #pragma unroll
    for (int f = 0; f < 4; ++f) {
        const float4* vp = (const float4*)&vs[f][row][xg * 4];
        const float4 A = vp[0], B = vp[1], Cq = vp[2], D = vp[3];
        const float win[16] = {A.x, A.y, A.z, A.w, B.x, B.y, B.z, B.w,
                               Cq.x, Cq.y, Cq.z, Cq.w, D.x, D.y, D.z, D.w};
        #pragma unroll
        for (int c = 0; c < 4; ++c) {
            float o = 0.f;
            #pragma unroll
            for (int k = 0; k < 11; ++k) o = fmaf(gw255[k], win[c + k], o);
            m[f][c] = o;
        }
    }
    float ssum = 0.f;
    if (oy < OUTD) {
        #pragma unroll
        for (int c = 0; c < 4; ++c) {
            if (ox0 + c < OUTD) {
                const float mr = m[0][c], md = m[1][c];
                const float ms = m[2][c], mp = m[3][c];
                const float mr2 = mr * mr, md2 = md * md, mpr = mr * md;
                const float s12 = mr2 + md2;
                const float num = fmaf(2.0f, mpr, C1F) * fmaf(2.0f, mp - mpr, C2F);
                const float den = (s12 + C1F) * ((ms - s12) + C2F);
                float r = __builtin_amdgcn_rcpf(den);
                r = r * fmaf(-den, r, 2.0f);      // 1 Newton step
                ssum += num * r;
            }
        }
    }

    // block reduction -> unique partial slot (no atomics)
    #pragma unroll
    for (int off = 32; off > 0; off >>= 1)
        ssum += __shfl_down(ssum, off, 64);
    const int lane = tid & 63, wv = tid >> 6;
    if (lane == 0) red[wv] = ssum;
    __syncthreads();
    if (tid == 0) {
        const float t = red[0] + red[1] + red[2] + red[3];
        partial[(size_t)b * SLOTS + (blockIdx.y * gridDim.x + blockIdx.x) * 3 + c3] = t;
    }
}

__global__ __launch_bounds__(128) void ssim_final(
        const float* __restrict__ partial, float* __restrict__ out) {
    __shared__ float red[2];
    const int b = blockIdx.x, tid = threadIdx.x;
    float s = 0.f;
    for (int i = tid; i < SLOTS; i += 128) s += partial[(size_t)b * SLOTS + i];
    #pragma unroll
    for (int off = 32; off > 0; off >>= 1) s += __shfl_down(s, off, 64);
    if ((tid & 63) == 0) red[tid >> 6] = s;
    __syncthreads();
    if (tid == 0) out[b] = (red[0] + red[1]) * (1.0f / NPIX);
}

extern "C" void kernel_launch(void* const* d_in, const int* in_sizes, int n_in,
                              void* d_out, int out_size, void* d_ws, size_t ws_size,
                              hipStream_t stream) {
    const float* raw = (const float*)d_in[0];
    const float* dst = (const float*)d_in[1];
    float* out     = (float*)d_out;
    float* partial = (float*)d_ws;   // 32*SLOTS fp32, fully overwritten each call

    dim3 grid(XBLK, YBLK, 96);       // 8 x 31 x (32 batches * 3 channels)
    ssim_main<<<grid, 256, 0, stream>>>(raw, dst, partial);
    ssim_final<<<32, 128, 0, stream>>>(partial, out);
}

// Round 6
// 288.420 us; speedup vs baseline: 1.0082x; 1.0082x over previous
//
#include <hip/hip_runtime.h>

// SSIM (32,3,512,512) fp32, crop 4, 11x11 Gaussian sigma=1.5, per-batch mean.
//
// V6 = V2 geometry (TH=32, 304 stage-A tasks — the empirical best) + V4 math
// (4 fields {r,d,r2+d2,rd}, folded 255, rcp+Newton) + the latency fix:
//   Stage A prefetches ALL 24 float4 row loads into registers before the
//   accumulation loop (fully unrolled). Compiler then emits staged
//   s_waitcnt vmcnt(N) waits -> ~one exposed latency per task instead of 12.
//   __launch_bounds__(256,2) raises the VGPR budget (~170 used, 3 waves/SIMD,
//   matching the 3-block/CU LDS cap at 51 KB).
// History: V4 (-20% ops) and V5 (TH=16, +occupancy theory) both LOST to V2
// => latency-bound, not op- or occupancy-theoretical-bound.

#define IMG   512
#define OUTD  494
#define CB    4
#define TW    64
#define TH    32
#define VSW   76           // 74 used; 4*42*76*4 = 51072 B -> 3 blocks/CU
#define C1F   6.5025f
#define C2F   58.5225f
#define NPIX  732108.0f    // 3*494*494
#define XBLK  8
#define YBLK  16
#define SLOTS (XBLK*YBLK*3)

__global__ __launch_bounds__(256, 2) void ssim_main(
        const float* __restrict__ raw, const float* __restrict__ dst,
        float* __restrict__ partial) {
    __shared__ float vs[4][TH + 10][VSW];
    __shared__ float red[4];

    const int tid = threadIdx.x;
    const int bc  = blockIdx.z;
    const int b   = bc / 3;
    const int c3  = bc - b * 3;
    const int ty0 = blockIdx.y * TH;
    const int tx0 = blockIdx.x * TW;

    // Gaussian weights: g = exp(-x^2/(2*1.5^2)); g /= sum(g)  (matches jnp)
    float gw[11], gw255[11];
    {
        float s = 0.f;
        #pragma unroll
        for (int k = 0; k < 11; ++k) {
            float x = (float)(k - 5);
            gw[k] = expf(-x * x * (1.0f / 4.5f));
            s += gw[k];
        }
        float inv = 1.0f / s;
        #pragma unroll
        for (int k = 0; k < 11; ++k) { gw[k] *= inv; gw255[k] = gw[k] * 255.0f; }
    }

    const float* rb = raw + (size_t)bc * (IMG * IMG);
    const float* db = dst + (size_t)bc * (IMG * IMG);

    // ---- Stage A: vertical conv. 304 tasks = 16 row-pairs x 19 x-groups. ----
    #pragma unroll 1
    for (int t = tid; t < 304; t += 256) {
        const int rp = t / 19;
        const int xg = t - rp * 19;
        int col0 = CB + tx0 + xg * 4;
        if (col0 > IMG - 4) col0 = IMG - 4;      // edge blocks: garbage cols unused
        int row0 = CB + ty0 + rp * 2;
        if (row0 > IMG - 12) row0 = IMG - 12;    // garbage rows unused

        // Deep prefetch: issue all 24 loads, THEN compute. Compiler pipelines
        // the consumption with staged vmcnt waits.
        float4 va[12], vc[12];
        {
            const float* rrow = rb + (size_t)row0 * IMG + col0;
            const float* drow = db + (size_t)row0 * IMG + col0;
            #pragma unroll
            for (int k = 0; k < 12; ++k) {
                va[k] = *(const float4*)(rrow); rrow += IMG;
                vc[k] = *(const float4*)(drow); drow += IMG;
            }
        }

        float a0[4][4] = {{0.f}};   // fields {r, d, r2+d2, rd} for vs-row rp*2
        float a1[4][4] = {{0.f}};   // and rp*2+1
        #pragma unroll
        for (int k = 0; k < 12; ++k) {
            const float A[4]  = {va[k].x, va[k].y, va[k].z, va[k].w};
            const float Cv[4] = {vc[k].x, vc[k].y, vc[k].z, vc[k].w};
            float s2[4], pq[4];
            #pragma unroll
            for (int c = 0; c < 4; ++c) {
                s2[c] = fmaf(A[c], A[c], Cv[c] * Cv[c]);
                pq[c] = A[c] * Cv[c];
            }
            if (k < 11) {
                const float w = gw[k], w2 = gw255[k];
                #pragma unroll
                for (int c = 0; c < 4; ++c) {
                    a0[0][c] = fmaf(w,  A[c],  a0[0][c]);
                    a0[1][c] = fmaf(w,  Cv[c], a0[1][c]);
                    a0[2][c] = fmaf(w2, s2[c], a0[2][c]);
                    a0[3][c] = fmaf(w2, pq[c], a0[3][c]);
                }
            }
            if (k >= 1) {
                const float w = gw[k - 1], w2 = gw255[k - 1];
                #pragma unroll
                for (int c = 0; c < 4; ++c) {
                    a1[0][c] = fmaf(w,  A[c],  a1[0][c]);
                    a1[1][c] = fmaf(w,  Cv[c], a1[1][c]);
                    a1[2][c] = fmaf(w2, s2[c], a1[2][c]);
                    a1[3][c] = fmaf(w2, pq[c], a1[3][c]);
                }
            }
        }
        #pragma unroll
        for (int f = 0; f < 4; ++f) {
            *(float4*)&vs[f][rp * 2 + 0][xg * 4] =
                make_float4(a0[f][0], a0[f][1], a0[f][2], a0[f][3]);
            *(float4*)&vs[f][rp * 2 + 1][xg * 4] =
                make_float4(a1[f][0], a1[f][1], a1[f][2], a1[f][3]);
        }
    }
    __syncthreads();

    // ---- Stage B: horizontal conv + SSIM. Thread = 4 cols x 2 rows. ----
    const int xg  = tid & 15;
    const int yt  = tid >> 4;
    const int ox0 = tx0 + xg * 4;
    float ssum = 0.f;
    #pragma unroll
    for (int r2 = 0; r2 < 2; ++r2) {
        const int row = yt * 2 + r2;
        const int oy  = ty0 + row;
        float m[4][4];
        #pragma unroll
        for (int f = 0; f < 4; ++f) {
            const float4* vp = (const float4*)&vs[f][row][xg * 4];
            const float4 A = vp[0], B = vp[1], Cq = vp[2], D = vp[3];
            const float win[16] = {A.x, A.y, A.z, A.w, B.x, B.y, B.z, B.w,
                                   Cq.x, Cq.y, Cq.z, Cq.w, D.x, D.y, D.z, D.w};
            #pragma unroll
            for (int c = 0; c < 4; ++c) {
                float o = 0.f;
                #pragma unroll
                for (int k = 0; k < 11; ++k) o = fmaf(gw255[k], win[c + k], o);
                m[f][c] = o;
            }
        }
        if (oy < OUTD) {
            #pragma unroll
            for (int c = 0; c < 4; ++c) {
                if (ox0 + c < OUTD) {
                    const float mr = m[0][c], md = m[1][c];
                    const float ms = m[2][c], mp = m[3][c];
                    const float mr2 = mr * mr, md2 = md * md, mpr = mr * md;
                    const float s12 = mr2 + md2;
                    const float num = fmaf(2.0f, mpr, C1F) * fmaf(2.0f, mp - mpr, C2F);
                    const float den = (s12 + C1F) * ((ms - s12) + C2F);
                    float r = __builtin_amdgcn_rcpf(den);
                    r = r * fmaf(-den, r, 2.0f);      // 1 Newton step
                    ssum += num * r;
                }
            }
        }
    }

    // block reduction -> unique partial slot (no atomics)
    #pragma unroll
    for (int off = 32; off > 0; off >>= 1)
        ssum += __shfl_down(ssum, off, 64);
    const int lane = tid & 63, wv = tid >> 6;
    if (lane == 0) red[wv] = ssum;
    __syncthreads();
    if (tid == 0) {
        const float t = red[0] + red[1] + red[2] + red[3];
        partial[(size_t)b * SLOTS + (blockIdx.y * gridDim.x + blockIdx.x) * 3 + c3] = t;
    }
}

__global__ __launch_bounds__(128) void ssim_final(
        const float* __restrict__ partial, float* __restrict__ out) {
    __shared__ float red[2];
    const int b = blockIdx.x, tid = threadIdx.x;
    float s = 0.f;
    for (int i = tid; i < SLOTS; i += 128) s += partial[(size_t)b * SLOTS + i];
    #pragma unroll
    for (int off = 32; off > 0; off >>= 1) s += __shfl_down(s, off, 64);
    if ((tid & 63) == 0) red[tid >> 6] = s;
    __syncthreads();
    if (tid == 0) out[b] = (red[0] + red[1]) * (1.0f / NPIX);
}

extern "C" void kernel_launch(void* const* d_in, const int* in_sizes, int n_in,
                              void* d_out, int out_size, void* d_ws, size_t ws_size,
                              hipStream_t stream) {
    const float* raw = (const float*)d_in[0];
    const float* dst = (const float*)d_in[1];
    float* out     = (float*)d_out;
    float* partial = (float*)d_ws;   // 32*SLOTS fp32, fully overwritten each call

    dim3 grid(XBLK, YBLK, 96);       // 8 x 16 x (32 batches * 3 channels)
    ssim_main<<<grid, 256, 0, stream>>>(raw, dst, partial);
    ssim_final<<<32, 128, 0, stream>>>(partial, out);
}